// Round 18
// baseline (221.854 us; speedup 1.0000x reference)
//
#include <hip/hip_runtime.h>
#include <hip/hip_fp16.h>

#define NN 50000
#define NE 800000
#define DIN 128
#define HD 128
#define CD 64
#define NB 196        // dst buckets of 256 nodes
#define BP 128        // partition blocks
#define EPB 6250      // edges per partition block
#define NP (NB * BP)  // 25088
#define NPCHUNK ((NP + 1023) / 1024)  // 25
#define G1B 782       // gemm1 blocks (ceil(50000/64))

typedef _Float16 h2 __attribute__((ext_vector_type(2)));
typedef _Float16 h4 __attribute__((ext_vector_type(4)));
typedef _Float16 h8 __attribute__((ext_vector_type(8)));

union H8 { h8 v; h2 p[4]; };
union H4 { h4 v; h2 p[2]; };

#if defined(__has_builtin)
#if __has_builtin(__builtin_amdgcn_fdot2)
#define FDOT2(a, b, c) __builtin_amdgcn_fdot2((a), (b), (c), false)
#endif
#endif
#ifndef FDOT2
#define FDOT2(a, b, c) ((c) + (float)(a)[0] * (float)(b)[0] + (float)(a)[1] * (float)(b)[1])
#endif

// ---------------- gp1: gemm1 (unscaled) fused with p1_hist ----------------
__global__ void __launch_bounds__(256) gp1(const float* __restrict__ x, const float* __restrict__ W1,
                                           __half* __restrict__ hs1,
                                           const int* __restrict__ dst, int* __restrict__ cntMatT) {
    __shared__ __align__(16) char smem[64 * 128 * 4 + 64 * 66 * 4];  // 48.5 KB
    if (blockIdx.x >= G1B) {  // ---- p1_hist ----
        int* hist = (int*)smem;
        int t = threadIdx.x, blk = blockIdx.x - G1B;
        if (t < NB) hist[t] = 0;
        __syncthreads();
        int base = blk * EPB;
        for (int i = base + t; i < base + EPB; i += 256)
            atomicAdd(&hist[dst[i] >> 8], 1);
        __syncthreads();
        if (t < NB) cntMatT[t * BP + blk] = hist[t];  // bucket-major
        return;
    }
    // ---- gemm1 ----
    h2* w2 = (h2*)smem;                    // [64 kp][128 c]
    h2* xs2 = (h2*)(smem + 64 * 128 * 4);  // [64 r][66 kp]
    int t = threadIdx.x;
    int row0 = blockIdx.x * 64;
#pragma unroll
    for (int i = 0; i < 32; ++i) {
        int idx = t + 256 * i;
        int kp = idx >> 7, c = idx & 127;
        h2 v;
        v[0] = (_Float16)W1[(2 * kp) * HD + c];
        v[1] = (_Float16)W1[(2 * kp + 1) * HD + c];
        w2[idx] = v;
    }
#pragma unroll
    for (int i = 0; i < 16; ++i) {
        int idx = t + 256 * i;
        int r = idx >> 6, kp = idx & 63;
        int gr = row0 + r; if (gr > NN - 1) gr = NN - 1;
        float2 f = ((const float2*)x)[(size_t)gr * 64 + kp];
        h2 v; v[0] = (_Float16)f.x; v[1] = (_Float16)f.y;
        xs2[r * 66 + kp] = v;
    }
    __syncthreads();

    int lane = t & 63, wv_id = t >> 6;
    int cl = lane & 15, g = lane >> 4;
    int wrow = wv_id * 16 + g * 4;
    int ca = 4 * cl, cb = 64 + 4 * cl;

    float acc[4][8];
#pragma unroll
    for (int r = 0; r < 4; ++r)
#pragma unroll
        for (int c = 0; c < 8; ++c) acc[r][c] = 0.f;

#pragma unroll 2
    for (int kq = 0; kq < 32; ++kq) {
        H4 xv[4];
#pragma unroll
        for (int r = 0; r < 4; ++r)
            xv[r].v = *(const h4*)&xs2[(wrow + r) * 66 + 2 * kq];
        H8 wa0, wa1, wb0, wb1;
        wa0.v = *(const h8*)&w2[(2 * kq) * 128 + ca];
        wa1.v = *(const h8*)&w2[(2 * kq + 1) * 128 + ca];
        wb0.v = *(const h8*)&w2[(2 * kq) * 128 + cb];
        wb1.v = *(const h8*)&w2[(2 * kq + 1) * 128 + cb];
#pragma unroll
        for (int r = 0; r < 4; ++r) {
            h2 x0 = xv[r].p[0];
            h2 x1 = xv[r].p[1];
#pragma unroll
            for (int cc = 0; cc < 4; ++cc) {
                acc[r][cc]     = FDOT2(x0, wa0.p[cc], acc[r][cc]);
                acc[r][cc]     = FDOT2(x1, wa1.p[cc], acc[r][cc]);
                acc[r][4 + cc] = FDOT2(x0, wb0.p[cc], acc[r][4 + cc]);
                acc[r][4 + cc] = FDOT2(x1, wb1.p[cc], acc[r][4 + cc]);
            }
        }
    }
#pragma unroll
    for (int rr = 0; rr < 4; ++rr) {
        int row = row0 + wrow + rr;
        if (row < NN) {
            union { __half2 h[2]; uint2 u; } pa, pb;
            pa.h[0] = __floats2half2_rn(acc[rr][0], acc[rr][1]);
            pa.h[1] = __floats2half2_rn(acc[rr][2], acc[rr][3]);
            pb.h[0] = __floats2half2_rn(acc[rr][4], acc[rr][5]);
            pb.h[1] = __floats2half2_rn(acc[rr][6], acc[rr][7]);
            *(uint2*)&hs1[(size_t)row * HD + ca] = pa.u;
            *(uint2*)&hs1[(size_t)row * HD + cb] = pb.u;
        }
    }
}

// ---------------- pscan_a: chunk-local exclusive scan + chunk totals ----------------
__global__ void __launch_bounds__(1024) pscan_a(int* __restrict__ c, int* __restrict__ sums) {
    __shared__ int wsum[16];
    int t = threadIdx.x;
    int i = blockIdx.x * 1024 + t;
    int v = (i < NP) ? c[i] : 0;
    int x = v;
#pragma unroll
    for (int off = 1; off < 64; off <<= 1) {
        int y = __shfl_up(x, off, 64);
        if ((t & 63) >= off) x += y;
    }
    int wid = t >> 6;
    if ((t & 63) == 63) wsum[wid] = x;
    __syncthreads();
    if (t < 16) {
        int s = wsum[t];
#pragma unroll
        for (int off = 1; off < 16; off <<= 1) {
            int y = __shfl_up(s, off, 16);
            if (t >= off) s += y;
        }
        wsum[t] = s;
    }
    __syncthreads();
    int basew = (wid > 0) ? wsum[wid - 1] : 0;
    int incl = basew + x;
    if (i < NP) c[i] = incl - v;  // chunk-local exclusive
    if (t == 1023) sums[blockIdx.x] = incl;
}

// ---------------- P3: partition edges (applies chunk bases locally) ----------------
__global__ void __launch_bounds__(256) p3_scatter(const int* __restrict__ src, const int* __restrict__ dst,
                                                  const int* __restrict__ cntMatT, const int* __restrict__ sums,
                                                  unsigned int* __restrict__ part) {
    __shared__ int cur[NB];
    __shared__ int sbase[NPCHUNK];
    int t = threadIdx.x, blk = blockIdx.x;
    if (t < 32) {
        int v = (t < NPCHUNK) ? sums[t] : 0;
        int x = v;
#pragma unroll
        for (int off = 1; off < 32; off <<= 1) {
            int y = __shfl_up(x, off, 32);
            if (t >= off) x += y;
        }
        if (t < NPCHUNK) sbase[t] = x - v;  // exclusive chunk bases
    }
    __syncthreads();
    if (t < NB) {
        int i = t * BP + blk;
        cur[t] = cntMatT[i] + sbase[i >> 10];
    }
    __syncthreads();
    int base = blk * EPB;
    for (int i = base + t; i < base + EPB; i += 256) {
        int d = dst[i];
        int b = d >> 8;
        int pos = atomicAdd(&cur[b], 1);
        part[pos] = (unsigned int)src[i] | ((unsigned int)(d & 255) << 16);
    }
}

// ---------------- fill2: per-bucket CSR build (emits rowptr starts + dinv + col) ----------------
__global__ void __launch_bounds__(256) fill2(const int* __restrict__ cntMatT, const int* __restrict__ sums,
                                             const unsigned int* __restrict__ part,
                                             int* __restrict__ rowptr, float* __restrict__ dinv,
                                             int* __restrict__ col) {
    __shared__ int cnt[256];
    __shared__ int wsum[4];
    __shared__ int sbase[NPCHUNK];
    int t = threadIdx.x, b = blockIdx.x;
    if (t < 32) {
        int v = (t < NPCHUNK) ? sums[t] : 0;
        int x = v;
#pragma unroll
        for (int off = 1; off < 32; off <<= 1) {
            int y = __shfl_up(x, off, 32);
            if (t >= off) x += y;
        }
        if (t < NPCHUNK) sbase[t] = x - v;
    }
    cnt[t] = 0;
    __syncthreads();
    int i0 = b * BP;
    int base = cntMatT[i0] + sbase[i0 >> 10];
    int endb = (b < NB - 1) ? (cntMatT[i0 + BP] + sbase[(i0 + BP) >> 10]) : NE;
    for (int i = base + t; i < endb; i += 256)
        atomicAdd(&cnt[part[i] >> 16], 1);
    __syncthreads();
    int v = cnt[t];
    int x = v;
#pragma unroll
    for (int off = 1; off < 64; off <<= 1) {
        int y = __shfl_up(x, off, 64);
        if ((t & 63) >= off) x += y;
    }
    int wid = t >> 6;
    if ((t & 63) == 63) wsum[wid] = x;
    __syncthreads();
    if (t < 4) {
        int s = wsum[t];
#pragma unroll
        for (int off = 1; off < 4; off <<= 1) {
            int y = __shfl_up(s, off, 4);
            if (t >= off) s += y;
        }
        wsum[t] = s;
    }
    __syncthreads();
    int bw = (wid > 0) ? wsum[wid - 1] : 0;
    int start = base + bw + x - v;
    int node = b * 256 + t;
    if (node < NN) {
        rowptr[node] = start;
        dinv[node] = rsqrtf((float)(v + 2));  // +2 self loops
    }
    __syncthreads();
    cnt[t] = start;
    __syncthreads();
    for (int i = base + t; i < endb; i += 256) {
        unsigned int u = part[i];
        int pos = atomicAdd(&cnt[u >> 16], 1);
        col[pos] = (int)(u & 0xFFFFu);
    }
    if (b == NB - 1 && t == 0) rowptr[NN] = NE;
}

// ---------------- agg1: 4 rows/wave, masked uniform-trip chains (16 gathers in flight) ----------------
__global__ void __launch_bounds__(256) agg1_csr(const int* __restrict__ rowptr, const int* __restrict__ col,
                                                const __half* __restrict__ hs1, const float* __restrict__ dinv,
                                                const float* __restrict__ b1, __half* __restrict__ h1h) {
    int t = threadIdx.x;
    int c2 = t & 63;
    int vb = blockIdx.x * 16 + (t >> 6) * 4;  // NN/16 = 3125 blocks
    const __half2* H = (const __half2*)hs1;   // row stride 64
    int j[4], e[4];
    float dv[4], ax[4], ay[4];
#pragma unroll
    for (int r = 0; r < 4; ++r) {
        int v = vb + r;
        j[r] = rowptr[v]; e[r] = rowptr[v + 1];
        dv[r] = dinv[v];
        float2 sf = __half22float2(H[(size_t)v * 64 + c2]);
        ax[r] = 2.f * dv[r] * sf.x; ay[r] = 2.f * dv[r] * sf.y;
    }
    // wave-uniform trip count = max chain length; tails clamped to row's last edge and masked
    int nit = 0;
#pragma unroll
    for (int r = 0; r < 4; ++r) {
        int n = (e[r] - j[r] + 3) >> 2;
        nit = (n > nit) ? n : nit;
    }
    for (; nit > 0; --nit) {
#pragma unroll
        for (int r = 0; r < 4; ++r) {
            int last = e[r] - 1;
#pragma unroll
            for (int i = 0; i < 4; ++i) {
                int ci = j[r] + i;
                int cc = ci < last ? ci : last;   // clamp to row's final edge (same line on tail)
                cc = cc > 0 ? cc : 0;
                int s = col[cc];
                float d = (ci < e[r]) ? dinv[s] : 0.f;
                float2 u = __half22float2(H[(size_t)s * 64 + c2]);
                ax[r] += d * u.x; ay[r] += d * u.y;
            }
            j[r] += 4;
        }
    }
    int c = c2 * 2;
    float bx = b1[c], by = b1[c + 1];
#pragma unroll
    for (int r = 0; r < 4; ++r) {
        float rx = fmaxf(dv[r] * ax[r] + bx, 0.f);
        float ry = fmaxf(dv[r] * ay[r] + by, 0.f);
        ((__half2*)h1h)[(size_t)(vb + r) * 64 + c2] = __floats2half2_rn(rx, ry);
    }
}

// ---------------- GEMM2: hs2(fp16) = h1(fp16) @ W2 (unscaled) ----------------
__global__ void __launch_bounds__(256, 4) gemm2(const __half* __restrict__ h1h, const float* __restrict__ W2,
                                                __half* __restrict__ hs2) {
    __shared__ h2 w2[64 * 64];    // 16 KB
    __shared__ h2 xs2[64 * 66];   // 16.9 KB
    int t = threadIdx.x;
    int row0 = blockIdx.x * 64;
    const h2* H = (const h2*)h1h;
#pragma unroll
    for (int i = 0; i < 16; ++i) {
        int idx = t + 256 * i;
        int kp = idx >> 6, c = idx & 63;
        h2 v;
        v[0] = (_Float16)W2[(2 * kp) * CD + c];
        v[1] = (_Float16)W2[(2 * kp + 1) * CD + c];
        w2[idx] = v;
    }
#pragma unroll
    for (int i = 0; i < 16; ++i) {
        int idx = t + 256 * i;
        int r = idx >> 6, kp = idx & 63;
        int gr = row0 + r; if (gr > NN - 1) gr = NN - 1;
        xs2[r * 66 + kp] = H[(size_t)gr * 64 + kp];  // fp16 passthrough
    }
    __syncthreads();

    int lane = t & 63, wv_id = t >> 6;
    int cl = lane & 15, g = lane >> 4;
    int wrow = wv_id * 16 + g * 4;
    int ca = 4 * cl;

    float acc[4][4];
#pragma unroll
    for (int r = 0; r < 4; ++r)
#pragma unroll
        for (int c = 0; c < 4; ++c) acc[r][c] = 0.f;

#pragma unroll 2
    for (int kq = 0; kq < 32; ++kq) {
        H4 xv[4];
#pragma unroll
        for (int r = 0; r < 4; ++r)
            xv[r].v = *(const h4*)&xs2[(wrow + r) * 66 + 2 * kq];
        H8 wa0, wa1;
        wa0.v = *(const h8*)&w2[(2 * kq) * 64 + ca];
        wa1.v = *(const h8*)&w2[(2 * kq + 1) * 64 + ca];
#pragma unroll
        for (int r = 0; r < 4; ++r) {
            h2 x0 = xv[r].p[0];
            h2 x1 = xv[r].p[1];
#pragma unroll
            for (int cc = 0; cc < 4; ++cc) {
                acc[r][cc] = FDOT2(x0, wa0.p[cc], acc[r][cc]);
                acc[r][cc] = FDOT2(x1, wa1.p[cc], acc[r][cc]);
            }
        }
    }
#pragma unroll
    for (int rr = 0; rr < 4; ++rr) {
        int row = row0 + wrow + rr;
        if (row < NN) {
            union { __half2 h[2]; uint2 u; } p;
            p.h[0] = __floats2half2_rn(acc[rr][0], acc[rr][1]);
            p.h[1] = __floats2half2_rn(acc[rr][2], acc[rr][3]);
            *(uint2*)&hs2[(size_t)row * CD + ca] = p.u;
        }
    }
}

// ---------------- agg2: 4 rows/wave, masked uniform-trip chains; + bias + log_softmax ----------------
__global__ void __launch_bounds__(256) agg2_csr(const int* __restrict__ rowptr, const int* __restrict__ col,
                                                const __half* __restrict__ hs2, const float* __restrict__ dinv,
                                                const float* __restrict__ b2, float* __restrict__ out) {
    int t = threadIdx.x;
    int c = t & 63;
    int vb = blockIdx.x * 16 + (t >> 6) * 4;
    int j[4], e[4];
    float dv[4], acc[4];
#pragma unroll
    for (int r = 0; r < 4; ++r) {
        int v = vb + r;
        j[r] = rowptr[v]; e[r] = rowptr[v + 1];
        dv[r] = dinv[v];
        acc[r] = 2.f * dv[r] * __half2float(hs2[(size_t)v * CD + c]);
    }
    int nit = 0;
#pragma unroll
    for (int r = 0; r < 4; ++r) {
        int n = (e[r] - j[r] + 3) >> 2;
        nit = (n > nit) ? n : nit;
    }
    for (; nit > 0; --nit) {
#pragma unroll
        for (int r = 0; r < 4; ++r) {
            int last = e[r] - 1;
#pragma unroll
            for (int i = 0; i < 4; ++i) {
                int ci = j[r] + i;
                int cc = ci < last ? ci : last;
                cc = cc > 0 ? cc : 0;
                int s = col[cc];
                float d = (ci < e[r]) ? dinv[s] : 0.f;
                acc[r] += d * __half2float(hs2[(size_t)s * CD + c]);
            }
            j[r] += 4;
        }
    }
    float b2c = b2[c];
#pragma unroll
    for (int r = 0; r < 4; ++r) {
        float o = dv[r] * acc[r] + b2c;
        float m = o;
#pragma unroll
        for (int off = 32; off >= 1; off >>= 1) m = fmaxf(m, __shfl_xor(m, off, 64));
        float ex = __expf(o - m);
        float s = ex;
#pragma unroll
        for (int off = 32; off >= 1; off >>= 1) s += __shfl_xor(s, off, 64);
        out[(size_t)(vb + r) * CD + c] = o - m - __logf(s);
    }
}

extern "C" void kernel_launch(void* const* d_in, const int* in_sizes, int n_in,
                              void* d_out, int out_size, void* d_ws, size_t ws_size,
                              hipStream_t stream) {
    const float* x  = (const float*)d_in[0];
    const int*   ei = (const int*)d_in[1];   // [2, E] int32
    const float* W1 = (const float*)d_in[2];
    const float* b1 = (const float*)d_in[3];
    const float* W2 = (const float*)d_in[4];
    const float* b2 = (const float*)d_in[5];
    float* out = (float*)d_out;

    const int* src = ei;
    const int* dst = ei + NE;

    float* ws = (float*)d_ws;
    float*        dinv    = ws;                              // NN floats
    int*          rowptr  = (int*)(ws + 65536);              // NN+1 ints
    int*          col     = (int*)(ws + 131072);             // NE ints -> 931072
    int*          cntMatT = (int*)(ws + 931136);             // NP ints
    int*          psums   = (int*)(ws + 956224);             // 25 ints
    unsigned int* part    = (unsigned int*)(ws + 960000);    // NE u32 -> 1760000
    __half*       hs1     = (__half*)(ws + 1760000);         // NN*HD halves -> 4960000
    __half*       h1h     = (__half*)(ws + 4960000);         // NN*HD halves -> 8160000
    __half*       hs2     = hs1;                             // reuse (hs1 dead after agg1)

    // 1) gemm1 (unscaled) fused with p1_hist
    gp1<<<G1B + BP, 256, 0, stream>>>(x, W1, hs1, dst, cntMatT);
    // 2) chunk-local scan of the (bucket,block) count matrix
    pscan_a<<<NPCHUNK, 1024, 0, stream>>>(cntMatT, psums);
    // 3) partition edges into bucket-major segments
    p3_scatter<<<BP, 256, 0, stream>>>(src, dst, cntMatT, psums, part);
    // 4) per-bucket CSR build (rowptr starts + dinv + col)
    fill2<<<NB, 256, 0, stream>>>(cntMatT, psums, part, rowptr, dinv, col);
    // 5) layer-1 aggregation (+ReLU), h1 in fp16; 4 rows/wave masked chains
    agg1_csr<<<NN / 16, 256, 0, stream>>>(rowptr, col, hs1, dinv, b1, h1h);
    // 6) layer-2 dense transform (fp16 in/out, unscaled)
    gemm2<<<(NN + 63) / 64, 256, 0, stream>>>(h1h, W2, hs2);
    // 7) layer-2 aggregation + bias + log_softmax; 4 rows/wave masked chains
    agg2_csr<<<NN / 16, 256, 0, stream>>>(rowptr, col, hs2, dinv, b2, out);
}

// Round 19
// 138.737 us; speedup vs baseline: 1.5991x; 1.5991x over previous
//
#include <hip/hip_runtime.h>
#include <hip/hip_fp16.h>

#define NN 50000
#define NE 800000
#define DIN 128
#define HD 128
#define CD 64
#define NB 196        // dst buckets of 256 nodes
#define BP 128        // partition blocks
#define EPB 6250      // edges per partition block
#define NP (NB * BP)  // 25088
#define NPCHUNK ((NP + 1023) / 1024)  // 25
#define G1B 782       // gemm1 blocks (ceil(50000/64))

typedef _Float16 h2 __attribute__((ext_vector_type(2)));
typedef _Float16 h4 __attribute__((ext_vector_type(4)));
typedef _Float16 h8 __attribute__((ext_vector_type(8)));

union H8 { h8 v; h2 p[4]; };
union H4 { h4 v; h2 p[2]; };

#if defined(__has_builtin)
#if __has_builtin(__builtin_amdgcn_fdot2)
#define FDOT2(a, b, c) __builtin_amdgcn_fdot2((a), (b), (c), false)
#endif
#endif
#ifndef FDOT2
#define FDOT2(a, b, c) ((c) + (float)(a)[0] * (float)(b)[0] + (float)(a)[1] * (float)(b)[1])
#endif

// ---------------- gp1: gemm1 (unscaled) fused with p1_hist ----------------
__global__ void __launch_bounds__(256) gp1(const float* __restrict__ x, const float* __restrict__ W1,
                                           __half* __restrict__ hs1,
                                           const int* __restrict__ dst, int* __restrict__ cntMatT) {
    __shared__ __align__(16) char smem[64 * 128 * 4 + 64 * 66 * 4];  // 48.5 KB
    if (blockIdx.x >= G1B) {  // ---- p1_hist ----
        int* hist = (int*)smem;
        int t = threadIdx.x, blk = blockIdx.x - G1B;
        if (t < NB) hist[t] = 0;
        __syncthreads();
        int base = blk * EPB;
        for (int i = base + t; i < base + EPB; i += 256)
            atomicAdd(&hist[dst[i] >> 8], 1);
        __syncthreads();
        if (t < NB) cntMatT[t * BP + blk] = hist[t];  // bucket-major
        return;
    }
    // ---- gemm1 ----
    h2* w2 = (h2*)smem;                    // [64 kp][128 c]
    h2* xs2 = (h2*)(smem + 64 * 128 * 4);  // [64 r][66 kp]
    int t = threadIdx.x;
    int row0 = blockIdx.x * 64;
#pragma unroll
    for (int i = 0; i < 32; ++i) {
        int idx = t + 256 * i;
        int kp = idx >> 7, c = idx & 127;
        h2 v;
        v[0] = (_Float16)W1[(2 * kp) * HD + c];
        v[1] = (_Float16)W1[(2 * kp + 1) * HD + c];
        w2[idx] = v;
    }
#pragma unroll
    for (int i = 0; i < 16; ++i) {
        int idx = t + 256 * i;
        int r = idx >> 6, kp = idx & 63;
        int gr = row0 + r; if (gr > NN - 1) gr = NN - 1;
        float2 f = ((const float2*)x)[(size_t)gr * 64 + kp];
        h2 v; v[0] = (_Float16)f.x; v[1] = (_Float16)f.y;
        xs2[r * 66 + kp] = v;
    }
    __syncthreads();

    int lane = t & 63, wv_id = t >> 6;
    int cl = lane & 15, g = lane >> 4;
    int wrow = wv_id * 16 + g * 4;
    int ca = 4 * cl, cb = 64 + 4 * cl;

    float acc[4][8];
#pragma unroll
    for (int r = 0; r < 4; ++r)
#pragma unroll
        for (int c = 0; c < 8; ++c) acc[r][c] = 0.f;

#pragma unroll 2
    for (int kq = 0; kq < 32; ++kq) {
        H4 xv[4];
#pragma unroll
        for (int r = 0; r < 4; ++r)
            xv[r].v = *(const h4*)&xs2[(wrow + r) * 66 + 2 * kq];
        H8 wa0, wa1, wb0, wb1;
        wa0.v = *(const h8*)&w2[(2 * kq) * 128 + ca];
        wa1.v = *(const h8*)&w2[(2 * kq + 1) * 128 + ca];
        wb0.v = *(const h8*)&w2[(2 * kq) * 128 + cb];
        wb1.v = *(const h8*)&w2[(2 * kq + 1) * 128 + cb];
#pragma unroll
        for (int r = 0; r < 4; ++r) {
            h2 x0 = xv[r].p[0];
            h2 x1 = xv[r].p[1];
#pragma unroll
            for (int cc = 0; cc < 4; ++cc) {
                acc[r][cc]     = FDOT2(x0, wa0.p[cc], acc[r][cc]);
                acc[r][cc]     = FDOT2(x1, wa1.p[cc], acc[r][cc]);
                acc[r][4 + cc] = FDOT2(x0, wb0.p[cc], acc[r][4 + cc]);
                acc[r][4 + cc] = FDOT2(x1, wb1.p[cc], acc[r][4 + cc]);
            }
        }
    }
#pragma unroll
    for (int rr = 0; rr < 4; ++rr) {
        int row = row0 + wrow + rr;
        if (row < NN) {
            union { __half2 h[2]; uint2 u; } pa, pb;
            pa.h[0] = __floats2half2_rn(acc[rr][0], acc[rr][1]);
            pa.h[1] = __floats2half2_rn(acc[rr][2], acc[rr][3]);
            pb.h[0] = __floats2half2_rn(acc[rr][4], acc[rr][5]);
            pb.h[1] = __floats2half2_rn(acc[rr][6], acc[rr][7]);
            *(uint2*)&hs1[(size_t)row * HD + ca] = pa.u;
            *(uint2*)&hs1[(size_t)row * HD + cb] = pb.u;
        }
    }
}

// ---------------- pscan_a: chunk-local exclusive scan + chunk totals ----------------
__global__ void __launch_bounds__(1024) pscan_a(int* __restrict__ c, int* __restrict__ sums) {
    __shared__ int wsum[16];
    int t = threadIdx.x;
    int i = blockIdx.x * 1024 + t;
    int v = (i < NP) ? c[i] : 0;
    int x = v;
#pragma unroll
    for (int off = 1; off < 64; off <<= 1) {
        int y = __shfl_up(x, off, 64);
        if ((t & 63) >= off) x += y;
    }
    int wid = t >> 6;
    if ((t & 63) == 63) wsum[wid] = x;
    __syncthreads();
    if (t < 16) {
        int s = wsum[t];
#pragma unroll
        for (int off = 1; off < 16; off <<= 1) {
            int y = __shfl_up(s, off, 16);
            if (t >= off) s += y;
        }
        wsum[t] = s;
    }
    __syncthreads();
    int basew = (wid > 0) ? wsum[wid - 1] : 0;
    int incl = basew + x;
    if (i < NP) c[i] = incl - v;  // chunk-local exclusive
    if (t == 1023) sums[blockIdx.x] = incl;
}

// ---------------- P3: partition edges (applies chunk bases locally) ----------------
__global__ void __launch_bounds__(256) p3_scatter(const int* __restrict__ src, const int* __restrict__ dst,
                                                  const int* __restrict__ cntMatT, const int* __restrict__ sums,
                                                  unsigned int* __restrict__ part) {
    __shared__ int cur[NB];
    __shared__ int sbase[NPCHUNK];
    int t = threadIdx.x, blk = blockIdx.x;
    if (t < 32) {
        int v = (t < NPCHUNK) ? sums[t] : 0;
        int x = v;
#pragma unroll
        for (int off = 1; off < 32; off <<= 1) {
            int y = __shfl_up(x, off, 32);
            if (t >= off) x += y;
        }
        if (t < NPCHUNK) sbase[t] = x - v;  // exclusive chunk bases
    }
    __syncthreads();
    if (t < NB) {
        int i = t * BP + blk;
        cur[t] = cntMatT[i] + sbase[i >> 10];
    }
    __syncthreads();
    int base = blk * EPB;
    for (int i = base + t; i < base + EPB; i += 256) {
        int d = dst[i];
        int b = d >> 8;
        int pos = atomicAdd(&cur[b], 1);
        part[pos] = (unsigned int)src[i] | ((unsigned int)(d & 255) << 16);
    }
}

// ---------------- fill2: per-bucket CSR build (emits rowptr starts + dinv + col) ----------------
__global__ void __launch_bounds__(256) fill2(const int* __restrict__ cntMatT, const int* __restrict__ sums,
                                             const unsigned int* __restrict__ part,
                                             int* __restrict__ rowptr, float* __restrict__ dinv,
                                             int* __restrict__ col) {
    __shared__ int cnt[256];
    __shared__ int wsum[4];
    __shared__ int sbase[NPCHUNK];
    int t = threadIdx.x, b = blockIdx.x;
    if (t < 32) {
        int v = (t < NPCHUNK) ? sums[t] : 0;
        int x = v;
#pragma unroll
        for (int off = 1; off < 32; off <<= 1) {
            int y = __shfl_up(x, off, 32);
            if (t >= off) x += y;
        }
        if (t < NPCHUNK) sbase[t] = x - v;
    }
    cnt[t] = 0;
    __syncthreads();
    int i0 = b * BP;
    int base = cntMatT[i0] + sbase[i0 >> 10];
    int endb = (b < NB - 1) ? (cntMatT[i0 + BP] + sbase[(i0 + BP) >> 10]) : NE;
    for (int i = base + t; i < endb; i += 256)
        atomicAdd(&cnt[part[i] >> 16], 1);
    __syncthreads();
    int v = cnt[t];
    int x = v;
#pragma unroll
    for (int off = 1; off < 64; off <<= 1) {
        int y = __shfl_up(x, off, 64);
        if ((t & 63) >= off) x += y;
    }
    int wid = t >> 6;
    if ((t & 63) == 63) wsum[wid] = x;
    __syncthreads();
    if (t < 4) {
        int s = wsum[t];
#pragma unroll
        for (int off = 1; off < 4; off <<= 1) {
            int y = __shfl_up(s, off, 4);
            if (t >= off) s += y;
        }
        wsum[t] = s;
    }
    __syncthreads();
    int bw = (wid > 0) ? wsum[wid - 1] : 0;
    int start = base + bw + x - v;
    int node = b * 256 + t;
    if (node < NN) {
        rowptr[node] = start;
        dinv[node] = rsqrtf((float)(v + 2));  // +2 self loops
    }
    __syncthreads();
    cnt[t] = start;
    __syncthreads();
    for (int i = base + t; i < endb; i += 256) {
        unsigned int u = part[i];
        int pos = atomicAdd(&cnt[u >> 16], 1);
        col[pos] = (int)(u & 0xFFFFu);
    }
    if (b == NB - 1 && t == 0) rowptr[NN] = NE;
}

// ---------------- agg1: 2 rows per wave, interleaved unroll-4 chains ----------------
__global__ void __launch_bounds__(256) agg1_csr(const int* __restrict__ rowptr, const int* __restrict__ col,
                                                const __half* __restrict__ hs1, const float* __restrict__ dinv,
                                                const float* __restrict__ b1, __half* __restrict__ h1h) {
    int t = threadIdx.x;
    int c2 = t & 63;
    int v0 = blockIdx.x * 8 + (t >> 6) * 2;   // NN/8 = 6250 blocks
    int v1 = v0 + 1;
    const __half2* H = (const __half2*)hs1;   // row stride 64
    int j0 = rowptr[v0], e0 = rowptr[v0 + 1];
    int j1 = rowptr[v1], e1 = rowptr[v1 + 1];
    float dv0 = dinv[v0], dv1 = dinv[v1];
    float2 sf0 = __half22float2(H[(size_t)v0 * 64 + c2]);
    float2 sf1 = __half22float2(H[(size_t)v1 * 64 + c2]);
    float ax0 = 2.f * dv0 * sf0.x, ay0 = 2.f * dv0 * sf0.y;
    float ax1 = 2.f * dv1 * sf1.x, ay1 = 2.f * dv1 * sf1.y;
    // interleaved main loop: 8 independent gathers in flight (4 per row)
    while (j0 + 4 <= e0 && j1 + 4 <= e1) {
        int a0 = col[j0], a1 = col[j0 + 1], a2 = col[j0 + 2], a3 = col[j0 + 3];
        int b0 = col[j1], b1_ = col[j1 + 1], b2 = col[j1 + 2], b3 = col[j1 + 3];
        float da0 = dinv[a0], da1 = dinv[a1], da2 = dinv[a2], da3 = dinv[a3];
        float db0 = dinv[b0], db1 = dinv[b1_], db2 = dinv[b2], db3 = dinv[b3];
        float2 va0 = __half22float2(H[(size_t)a0 * 64 + c2]);
        float2 va1 = __half22float2(H[(size_t)a1 * 64 + c2]);
        float2 va2 = __half22float2(H[(size_t)a2 * 64 + c2]);
        float2 va3 = __half22float2(H[(size_t)a3 * 64 + c2]);
        float2 vb0 = __half22float2(H[(size_t)b0 * 64 + c2]);
        float2 vb1 = __half22float2(H[(size_t)b1_ * 64 + c2]);
        float2 vb2 = __half22float2(H[(size_t)b2 * 64 + c2]);
        float2 vb3 = __half22float2(H[(size_t)b3 * 64 + c2]);
        ax0 += da0 * va0.x + da1 * va1.x + da2 * va2.x + da3 * va3.x;
        ay0 += da0 * va0.y + da1 * va1.y + da2 * va2.y + da3 * va3.y;
        ax1 += db0 * vb0.x + db1 * vb1.x + db2 * vb2.x + db3 * vb3.x;
        ay1 += db0 * vb0.y + db1 * vb1.y + db2 * vb2.y + db3 * vb3.y;
        j0 += 4; j1 += 4;
    }
    for (; j0 + 4 <= e0; j0 += 4) {
        int a0 = col[j0], a1 = col[j0 + 1], a2 = col[j0 + 2], a3 = col[j0 + 3];
        float da0 = dinv[a0], da1 = dinv[a1], da2 = dinv[a2], da3 = dinv[a3];
        float2 va0 = __half22float2(H[(size_t)a0 * 64 + c2]);
        float2 va1 = __half22float2(H[(size_t)a1 * 64 + c2]);
        float2 va2 = __half22float2(H[(size_t)a2 * 64 + c2]);
        float2 va3 = __half22float2(H[(size_t)a3 * 64 + c2]);
        ax0 += da0 * va0.x + da1 * va1.x + da2 * va2.x + da3 * va3.x;
        ay0 += da0 * va0.y + da1 * va1.y + da2 * va2.y + da3 * va3.y;
    }
    for (; j0 < e0; ++j0) {
        int s = col[j0];
        float ds = dinv[s];
        float2 u = __half22float2(H[(size_t)s * 64 + c2]);
        ax0 += ds * u.x; ay0 += ds * u.y;
    }
    for (; j1 + 4 <= e1; j1 += 4) {
        int b0 = col[j1], b1_ = col[j1 + 1], b2 = col[j1 + 2], b3 = col[j1 + 3];
        float db0 = dinv[b0], db1 = dinv[b1_], db2 = dinv[b2], db3 = dinv[b3];
        float2 vb0 = __half22float2(H[(size_t)b0 * 64 + c2]);
        float2 vb1 = __half22float2(H[(size_t)b1_ * 64 + c2]);
        float2 vb2 = __half22float2(H[(size_t)b2 * 64 + c2]);
        float2 vb3 = __half22float2(H[(size_t)b3 * 64 + c2]);
        ax1 += db0 * vb0.x + db1 * vb1.x + db2 * vb2.x + db3 * vb3.x;
        ay1 += db0 * vb0.y + db1 * vb1.y + db2 * vb2.y + db3 * vb3.y;
    }
    for (; j1 < e1; ++j1) {
        int s = col[j1];
        float ds = dinv[s];
        float2 u = __half22float2(H[(size_t)s * 64 + c2]);
        ax1 += ds * u.x; ay1 += ds * u.y;
    }
    int c = c2 * 2;
    float bx = b1[c], by = b1[c + 1];
    float r0x = fmaxf(dv0 * ax0 + bx, 0.f);
    float r0y = fmaxf(dv0 * ay0 + by, 0.f);
    float r1x = fmaxf(dv1 * ax1 + bx, 0.f);
    float r1y = fmaxf(dv1 * ay1 + by, 0.f);
    ((__half2*)h1h)[(size_t)v0 * 64 + c2] = __floats2half2_rn(r0x, r0y);
    ((__half2*)h1h)[(size_t)v1 * 64 + c2] = __floats2half2_rn(r1x, r1y);
}

// ---------------- GEMM2: hs2(fp16) = h1(fp16) @ W2 (unscaled) ----------------
__global__ void __launch_bounds__(256, 4) gemm2(const __half* __restrict__ h1h, const float* __restrict__ W2,
                                                __half* __restrict__ hs2) {
    __shared__ h2 w2[64 * 64];    // 16 KB
    __shared__ h2 xs2[64 * 66];   // 16.9 KB
    int t = threadIdx.x;
    int row0 = blockIdx.x * 64;
    const h2* H = (const h2*)h1h;
#pragma unroll
    for (int i = 0; i < 16; ++i) {
        int idx = t + 256 * i;
        int kp = idx >> 6, c = idx & 63;
        h2 v;
        v[0] = (_Float16)W2[(2 * kp) * CD + c];
        v[1] = (_Float16)W2[(2 * kp + 1) * CD + c];
        w2[idx] = v;
    }
#pragma unroll
    for (int i = 0; i < 16; ++i) {
        int idx = t + 256 * i;
        int r = idx >> 6, kp = idx & 63;
        int gr = row0 + r; if (gr > NN - 1) gr = NN - 1;
        xs2[r * 66 + kp] = H[(size_t)gr * 64 + kp];  // fp16 passthrough
    }
    __syncthreads();

    int lane = t & 63, wv_id = t >> 6;
    int cl = lane & 15, g = lane >> 4;
    int wrow = wv_id * 16 + g * 4;
    int ca = 4 * cl;

    float acc[4][4];
#pragma unroll
    for (int r = 0; r < 4; ++r)
#pragma unroll
        for (int c = 0; c < 4; ++c) acc[r][c] = 0.f;

#pragma unroll 2
    for (int kq = 0; kq < 32; ++kq) {
        H4 xv[4];
#pragma unroll
        for (int r = 0; r < 4; ++r)
            xv[r].v = *(const h4*)&xs2[(wrow + r) * 66 + 2 * kq];
        H8 wa0, wa1;
        wa0.v = *(const h8*)&w2[(2 * kq) * 64 + ca];
        wa1.v = *(const h8*)&w2[(2 * kq + 1) * 64 + ca];
#pragma unroll
        for (int r = 0; r < 4; ++r) {
            h2 x0 = xv[r].p[0];
            h2 x1 = xv[r].p[1];
#pragma unroll
            for (int cc = 0; cc < 4; ++cc) {
                acc[r][cc] = FDOT2(x0, wa0.p[cc], acc[r][cc]);
                acc[r][cc] = FDOT2(x1, wa1.p[cc], acc[r][cc]);
            }
        }
    }
#pragma unroll
    for (int rr = 0; rr < 4; ++rr) {
        int row = row0 + wrow + rr;
        if (row < NN) {
            union { __half2 h[2]; uint2 u; } p;
            p.h[0] = __floats2half2_rn(acc[rr][0], acc[rr][1]);
            p.h[1] = __floats2half2_rn(acc[rr][2], acc[rr][3]);
            *(uint2*)&hs2[(size_t)row * CD + ca] = p.u;
        }
    }
}

// ---------------- agg2: 2 rows per wave, interleaved; + bias + log_softmax ----------------
__global__ void __launch_bounds__(256) agg2_csr(const int* __restrict__ rowptr, const int* __restrict__ col,
                                                const __half* __restrict__ hs2, const float* __restrict__ dinv,
                                                const float* __restrict__ b2, float* __restrict__ out) {
    int t = threadIdx.x;
    int c = t & 63;
    int v0 = blockIdx.x * 8 + (t >> 6) * 2;
    int v1 = v0 + 1;
    int j0 = rowptr[v0], e0 = rowptr[v0 + 1];
    int j1 = rowptr[v1], e1 = rowptr[v1 + 1];
    float dv0 = dinv[v0], dv1 = dinv[v1];
    float acc0 = 2.f * dv0 * __half2float(hs2[(size_t)v0 * CD + c]);
    float acc1 = 2.f * dv1 * __half2float(hs2[(size_t)v1 * CD + c]);
    while (j0 + 4 <= e0 && j1 + 4 <= e1) {
        int a0 = col[j0], a1 = col[j0 + 1], a2 = col[j0 + 2], a3 = col[j0 + 3];
        int b0 = col[j1], b1_ = col[j1 + 1], b2_ = col[j1 + 2], b3 = col[j1 + 3];
        float da0 = dinv[a0], da1 = dinv[a1], da2 = dinv[a2], da3 = dinv[a3];
        float db0 = dinv[b0], db1 = dinv[b1_], db2 = dinv[b2_], db3 = dinv[b3];
        float fa0 = __half2float(hs2[(size_t)a0 * CD + c]), fa1 = __half2float(hs2[(size_t)a1 * CD + c]);
        float fa2 = __half2float(hs2[(size_t)a2 * CD + c]), fa3 = __half2float(hs2[(size_t)a3 * CD + c]);
        float fb0 = __half2float(hs2[(size_t)b0 * CD + c]), fb1 = __half2float(hs2[(size_t)b1_ * CD + c]);
        float fb2 = __half2float(hs2[(size_t)b2_ * CD + c]), fb3 = __half2float(hs2[(size_t)b3 * CD + c]);
        acc0 += da0 * fa0 + da1 * fa1 + da2 * fa2 + da3 * fa3;
        acc1 += db0 * fb0 + db1 * fb1 + db2 * fb2 + db3 * fb3;
        j0 += 4; j1 += 4;
    }
    for (; j0 + 4 <= e0; j0 += 4) {
        int a0 = col[j0], a1 = col[j0 + 1], a2 = col[j0 + 2], a3 = col[j0 + 3];
        float da0 = dinv[a0], da1 = dinv[a1], da2 = dinv[a2], da3 = dinv[a3];
        float fa0 = __half2float(hs2[(size_t)a0 * CD + c]), fa1 = __half2float(hs2[(size_t)a1 * CD + c]);
        float fa2 = __half2float(hs2[(size_t)a2 * CD + c]), fa3 = __half2float(hs2[(size_t)a3 * CD + c]);
        acc0 += da0 * fa0 + da1 * fa1 + da2 * fa2 + da3 * fa3;
    }
    for (; j0 < e0; ++j0) {
        int s = col[j0];
        acc0 += dinv[s] * __half2float(hs2[(size_t)s * CD + c]);
    }
    for (; j1 + 4 <= e1; j1 += 4) {
        int b0 = col[j1], b1_ = col[j1 + 1], b2_ = col[j1 + 2], b3 = col[j1 + 3];
        float db0 = dinv[b0], db1 = dinv[b1_], db2 = dinv[b2_], db3 = dinv[b3];
        float fb0 = __half2float(hs2[(size_t)b0 * CD + c]), fb1 = __half2float(hs2[(size_t)b1_ * CD + c]);
        float fb2 = __half2float(hs2[(size_t)b2_ * CD + c]), fb3 = __half2float(hs2[(size_t)b3 * CD + c]);
        acc1 += db0 * fb0 + db1 * fb1 + db2 * fb2 + db3 * fb3;
    }
    for (; j1 < e1; ++j1) {
        int s = col[j1];
        acc1 += dinv[s] * __half2float(hs2[(size_t)s * CD + c]);
    }
    float b2c = b2[c];
    // row v0 softmax
    float o0 = dv0 * acc0 + b2c;
    float m0 = o0;
#pragma unroll
    for (int off = 32; off >= 1; off >>= 1) m0 = fmaxf(m0, __shfl_xor(m0, off, 64));
    float ex0 = __expf(o0 - m0);
    float s0 = ex0;
#pragma unroll
    for (int off = 32; off >= 1; off >>= 1) s0 += __shfl_xor(s0, off, 64);
    out[(size_t)v0 * CD + c] = o0 - m0 - __logf(s0);
    // row v1 softmax
    float o1 = dv1 * acc1 + b2c;
    float m1 = o1;
#pragma unroll
    for (int off = 32; off >= 1; off >>= 1) m1 = fmaxf(m1, __shfl_xor(m1, off, 64));
    float ex1 = __expf(o1 - m1);
    float s1 = ex1;
#pragma unroll
    for (int off = 32; off >= 1; off >>= 1) s1 += __shfl_xor(s1, off, 64);
    out[(size_t)v1 * CD + c] = o1 - m1 - __logf(s1);
}

extern "C" void kernel_launch(void* const* d_in, const int* in_sizes, int n_in,
                              void* d_out, int out_size, void* d_ws, size_t ws_size,
                              hipStream_t stream) {
    const float* x  = (const float*)d_in[0];
    const int*   ei = (const int*)d_in[1];   // [2, E] int32
    const float* W1 = (const float*)d_in[2];
    const float* b1 = (const float*)d_in[3];
    const float* W2 = (const float*)d_in[4];
    const float* b2 = (const float*)d_in[5];
    float* out = (float*)d_out;

    const int* src = ei;
    const int* dst = ei + NE;

    float* ws = (float*)d_ws;
    float*        dinv    = ws;                              // NN floats
    int*          rowptr  = (int*)(ws + 65536);              // NN+1 ints
    int*          col     = (int*)(ws + 131072);             // NE ints -> 931072
    int*          cntMatT = (int*)(ws + 931136);             // NP ints
    int*          psums   = (int*)(ws + 956224);             // 25 ints
    unsigned int* part    = (unsigned int*)(ws + 960000);    // NE u32 -> 1760000
    __half*       hs1     = (__half*)(ws + 1760000);         // NN*HD halves -> 4960000
    __half*       h1h     = (__half*)(ws + 4960000);         // NN*HD halves -> 8160000
    __half*       hs2     = hs1;                             // reuse (hs1 dead after agg1)

    // 1) gemm1 (unscaled) fused with p1_hist
    gp1<<<G1B + BP, 256, 0, stream>>>(x, W1, hs1, dst, cntMatT);
    // 2) chunk-local scan of the (bucket,block) count matrix
    pscan_a<<<NPCHUNK, 1024, 0, stream>>>(cntMatT, psums);
    // 3) partition edges into bucket-major segments
    p3_scatter<<<BP, 256, 0, stream>>>(src, dst, cntMatT, psums, part);
    // 4) per-bucket CSR build (rowptr starts + dinv + col)
    fill2<<<NB, 256, 0, stream>>>(cntMatT, psums, part, rowptr, dinv, col);
    // 5) layer-1 aggregation (+ReLU), h1 in fp16; 2 rows/wave
    agg1_csr<<<NN / 8, 256, 0, stream>>>(rowptr, col, hs1, dinv, b1, h1h);
    // 6) layer-2 dense transform (fp16 in/out, unscaled)
    gemm2<<<(NN + 63) / 64, 256, 0, stream>>>(h1h, W2, hs2);
    // 7) layer-2 aggregation + bias + log_softmax; 2 rows/wave
    agg2_csr<<<NN / 8, 256, 0, stream>>>(rowptr, col, hs2, dinv, b2, out);
}